// Round 1
// baseline (367.460 us; speedup 1.0000x reference)
//
#include <hip/hip_runtime.h>
#include <hip/hip_bf16.h>
#include <math.h>

#define N_LEFTC  5000
#define N_RIGHTC 20000
#define NEDGE    400000
#define HIDC     128
#define NHC      8
#define HDC      16

// ---------------------------------------------------------------------------
// Generic fp32 GEMM: C[M][128] = A[M][128] @ B[128][128] (+bias, +relu)
// block 256 threads, tile 64 rows x 128 cols, K-step 32
// ---------------------------------------------------------------------------
template<bool BIAS, bool RELU>
__global__ __launch_bounds__(256) void gemm128(const float* __restrict__ A,
                                               const float* __restrict__ B,
                                               const float* __restrict__ bias,
                                               float* __restrict__ C, int M)
{
    __shared__ float As[64][33];
    __shared__ float Bs[32][132];
    const int tid  = threadIdx.x;
    const int row0 = blockIdx.x * 64;
    const int rg   = tid >> 5;      // 0..7 (8 rows each)
    const int c0   = (tid & 31) * 4; // col quad

    float acc[8][4] = {};

    for (int k0 = 0; k0 < 128; k0 += 32) {
        // A tile 64x32 (512 float4)
        for (int l = tid; l < 512; l += 256) {
            int r  = l >> 3;
            int cv = (l & 7) * 4;
            float4 a = make_float4(0.f, 0.f, 0.f, 0.f);
            if (row0 + r < M)
                a = *(const float4*)&A[(size_t)(row0 + r) * 128 + k0 + cv];
            As[r][cv + 0] = a.x; As[r][cv + 1] = a.y;
            As[r][cv + 2] = a.z; As[r][cv + 3] = a.w;
        }
        // B tile 32x128 (1024 float4)
        for (int l = tid; l < 1024; l += 256) {
            int r  = l >> 5;
            int cv = (l & 31) * 4;
            float4 b = *(const float4*)&B[(size_t)(k0 + r) * 128 + cv];
            Bs[r][cv + 0] = b.x; Bs[r][cv + 1] = b.y;
            Bs[r][cv + 2] = b.z; Bs[r][cv + 3] = b.w;
        }
        __syncthreads();
        #pragma unroll
        for (int kk = 0; kk < 32; ++kk) {
            float b0 = Bs[kk][c0 + 0], b1 = Bs[kk][c0 + 1];
            float b2 = Bs[kk][c0 + 2], b3 = Bs[kk][c0 + 3];
            #pragma unroll
            for (int i = 0; i < 8; ++i) {
                float av = As[rg * 8 + i][kk];
                acc[i][0] += av * b0; acc[i][1] += av * b1;
                acc[i][2] += av * b2; acc[i][3] += av * b3;
            }
        }
        __syncthreads();
    }
    #pragma unroll
    for (int i = 0; i < 8; ++i) {
        int r = row0 + rg * 8 + i;
        if (r < M) {
            float o0 = acc[i][0], o1 = acc[i][1], o2 = acc[i][2], o3 = acc[i][3];
            if (BIAS) { o0 += bias[c0]; o1 += bias[c0+1]; o2 += bias[c0+2]; o3 += bias[c0+3]; }
            if (RELU) { o0 = fmaxf(o0,0.f); o1 = fmaxf(o1,0.f); o2 = fmaxf(o2,0.f); o3 = fmaxf(o3,0.f); }
            float4 o = make_float4(o0, o1, o2, o3);
            *(float4*)&C[(size_t)r * 128 + c0] = o;
        }
    }
}

// ---------------------------------------------------------------------------
// Concat-GEMM: C[M][128] = relu( [bn(A1), A2] @ B[256][128] + bias )
// bn(x)[col k] = A1[r][k]*bnp[k] + bnp[128+k]
// ---------------------------------------------------------------------------
__global__ __launch_bounds__(256) void gemm_cat(const float* __restrict__ A1,
                                                const float* __restrict__ A2,
                                                const float* __restrict__ bnp,
                                                const float* __restrict__ B,
                                                const float* __restrict__ bias,
                                                float* __restrict__ C, int M)
{
    __shared__ float As[64][33];
    __shared__ float Bs[32][132];
    const int tid  = threadIdx.x;
    const int row0 = blockIdx.x * 64;
    const int rg   = tid >> 5;
    const int c0   = (tid & 31) * 4;

    float acc[8][4] = {};

    for (int k0 = 0; k0 < 256; k0 += 32) {
        for (int l = tid; l < 512; l += 256) {
            int r  = l >> 3;
            int cv = (l & 7) * 4;
            int k  = k0 + cv;
            float4 a = make_float4(0.f, 0.f, 0.f, 0.f);
            if (row0 + r < M) {
                if (k < 128) {
                    a = *(const float4*)&A1[(size_t)(row0 + r) * 128 + k];
                    float4 sc = *(const float4*)&bnp[k];
                    float4 sh = *(const float4*)&bnp[128 + k];
                    a.x = a.x * sc.x + sh.x; a.y = a.y * sc.y + sh.y;
                    a.z = a.z * sc.z + sh.z; a.w = a.w * sc.w + sh.w;
                } else {
                    a = *(const float4*)&A2[(size_t)(row0 + r) * 128 + (k - 128)];
                }
            }
            As[r][cv + 0] = a.x; As[r][cv + 1] = a.y;
            As[r][cv + 2] = a.z; As[r][cv + 3] = a.w;
        }
        for (int l = tid; l < 1024; l += 256) {
            int r  = l >> 5;
            int cv = (l & 31) * 4;
            float4 b = *(const float4*)&B[(size_t)(k0 + r) * 128 + cv];
            Bs[r][cv + 0] = b.x; Bs[r][cv + 1] = b.y;
            Bs[r][cv + 2] = b.z; Bs[r][cv + 3] = b.w;
        }
        __syncthreads();
        #pragma unroll
        for (int kk = 0; kk < 32; ++kk) {
            float b0 = Bs[kk][c0 + 0], b1 = Bs[kk][c0 + 1];
            float b2 = Bs[kk][c0 + 2], b3 = Bs[kk][c0 + 3];
            #pragma unroll
            for (int i = 0; i < 8; ++i) {
                float av = As[rg * 8 + i][kk];
                acc[i][0] += av * b0; acc[i][1] += av * b1;
                acc[i][2] += av * b2; acc[i][3] += av * b3;
            }
        }
        __syncthreads();
    }
    #pragma unroll
    for (int i = 0; i < 8; ++i) {
        int r = row0 + rg * 8 + i;
        if (r < M) {
            float o0 = acc[i][0] + bias[c0+0];
            float o1 = acc[i][1] + bias[c0+1];
            float o2 = acc[i][2] + bias[c0+2];
            float o3 = acc[i][3] + bias[c0+3];
            o0 = fmaxf(o0,0.f); o1 = fmaxf(o1,0.f); o2 = fmaxf(o2,0.f); o3 = fmaxf(o3,0.f);
            float4 o = make_float4(o0, o1, o2, o3);
            *(float4*)&C[(size_t)r * 128 + c0] = o;
        }
    }
}

// ---------------------------------------------------------------------------
// CSR build: histogram -> scan -> scatter
// ---------------------------------------------------------------------------
__global__ void hist_kernel(const int* __restrict__ edst, int* __restrict__ counts)
{
    for (int i = blockIdx.x * blockDim.x + threadIdx.x; i < NEDGE; i += gridDim.x * blockDim.x)
        atomicAdd(&counts[edst[i]], 1);
}

__global__ void scan_kernel(const int* __restrict__ counts, int* __restrict__ starts,
                            int* __restrict__ cursors)
{
    __shared__ int part[256];
    const int CH = (N_RIGHTC + 255) / 256;   // 79
    int t  = threadIdx.x;
    int lo = t * CH;
    int hi = lo + CH; if (hi > N_RIGHTC) hi = N_RIGHTC;
    int sum = 0;
    for (int i = lo; i < hi; ++i) sum += counts[i];
    part[t] = sum;
    __syncthreads();
    if (t == 0) {
        int run = 0;
        for (int i = 0; i < 256; ++i) { int c = part[i]; part[i] = run; run += c; }
        starts[N_RIGHTC] = run;
    }
    __syncthreads();
    int run = part[t];
    for (int i = lo; i < hi; ++i) {
        starts[i]  = run;
        cursors[i] = run;
        run += counts[i];
    }
}

__global__ void scatter_kernel(const int* __restrict__ edst, int* __restrict__ cursors,
                               int* __restrict__ sorted)
{
    for (int i = blockIdx.x * blockDim.x + threadIdx.x; i < NEDGE; i += gridDim.x * blockDim.x) {
        int d = edst[i];
        int p = atomicAdd(&cursors[d], 1);
        sorted[p] = i;
    }
}

// ---------------------------------------------------------------------------
// Fused edge attention: one block (256 thr = 2 edge streams x 128 slots) per dst
// ---------------------------------------------------------------------------
__global__ __launch_bounds__(256) void attn_kernel(
    const float* __restrict__ qproj, const float* __restrict__ kproj,
    const float* __restrict__ vproj, const float* __restrict__ ef,
    const int* __restrict__ esrc, const int* __restrict__ sorted,
    const int* __restrict__ starts, const float* __restrict__ Wke,
    const float* __restrict__ Wve, float* __restrict__ agg)
{
    const int d = blockIdx.x;
    const int t = threadIdx.x & 127;   // (h,d) slot = column
    const int g = threadIdx.x >> 7;    // edge stream 0/1

    __shared__ float sWke[512];
    __shared__ float sWve[512];
    for (int i = threadIdx.x; i < 512; i += 256) { sWke[i] = Wke[i]; sWve[i] = Wve[i]; }
    __syncthreads();

    const float q = qproj[(size_t)d * 128 + t];
    const int e0 = starts[d], e1 = starts[d + 1];

    float m = -INFINITY, s = 0.f, acc = 0.f;

    for (int i = e0 + g; i < e1; i += 2) {
        int eid = sorted[i];
        int src = esrc[eid];
        float4 f = *(const float4*)&ef[(size_t)eid * 4];
        float ke = f.x * sWke[t] + f.y * sWke[128 + t] + f.z * sWke[256 + t] + f.w * sWke[384 + t];
        float ve = f.x * sWve[t] + f.y * sWve[128 + t] + f.z * sWve[256 + t] + f.w * sWve[384 + t];
        float k = kproj[(size_t)src * 128 + t];
        float v = vproj[(size_t)src * 128 + t];
        float p = q * (k + ke);
        p += __shfl_xor(p, 1);
        p += __shfl_xor(p, 2);
        p += __shfl_xor(p, 4);
        p += __shfl_xor(p, 8);
        float logit = p * 0.25f;           // 1/sqrt(16)
        float nm  = fmaxf(m, logit);
        float fac = __expf(m - nm);        // m=-inf on first iter -> fac=0
        float e   = __expf(logit - nm);
        s   = s * fac + e;
        acc = acc * fac + e * (v + ve);
        m   = nm;
    }

    // merge the two streams
    __shared__ float sm[128], ss[128], sa[128];
    if (g == 1) { sm[t] = m; ss[t] = s; sa[t] = acc; }
    __syncthreads();
    if (g == 0) {
        float m2 = sm[t], s2 = ss[t], a2 = sa[t];
        float nm = fmaxf(m, m2);
        float f1 = (m  > -INFINITY) ? __expf(m  - nm) : 0.f;
        float f2 = (m2 > -INFINITY) ? __expf(m2 - nm) : 0.f;
        float S = s * f1 + s2 * f2;
        float A = acc * f1 + a2 * f2;
        agg[(size_t)d * 128 + t] = A / (S + 1e-16f);
    }
}

// ---------------------------------------------------------------------------
// BatchNorm stats + finalize
// ---------------------------------------------------------------------------
__global__ void bn_stats(const float* __restrict__ X, float* __restrict__ stats)
{
    const int col = threadIdx.x & 127;
    const int rg  = threadIdx.x >> 7;
    float s = 0.f, q = 0.f;
    for (int r = blockIdx.x * 2 + rg; r < N_RIGHTC; r += gridDim.x * 2) {
        float v = X[(size_t)r * 128 + col];
        s += v; q += v * v;
    }
    __shared__ float ls[256], lq[256];
    ls[threadIdx.x] = s; lq[threadIdx.x] = q;
    __syncthreads();
    if (rg == 0) {
        s = ls[col] + ls[128 + col];
        q = lq[col] + lq[128 + col];
        atomicAdd(&stats[col], s);
        atomicAdd(&stats[128 + col], q);
    }
}

__global__ void bn_finalize(const float* __restrict__ stats, const float* __restrict__ gamma,
                            const float* __restrict__ beta, float* __restrict__ bnp)
{
    int c = threadIdx.x;
    float mean = stats[c] * (1.f / N_RIGHTC);
    float var  = stats[128 + c] * (1.f / N_RIGHTC) - mean * mean;
    float sc   = gamma[c] * rsqrtf(var + 1e-5f);
    bnp[c]       = sc;
    bnp[128 + c] = beta[c] - mean * sc;
}

// ---------------------------------------------------------------------------
// launch
// ---------------------------------------------------------------------------
extern "C" void kernel_launch(void* const* d_in, const int* in_sizes, int n_in,
                              void* d_out, int out_size, void* d_ws, size_t ws_size,
                              hipStream_t stream)
{
    const float* left  = (const float*)d_in[0];
    const float* right = (const float*)d_in[1];
    const float* ef    = (const float*)d_in[2];
    const int*   esrc  = (const int*)d_in[3];
    const int*   edst  = (const int*)d_in[4];
    const float* Wq    = (const float*)d_in[5];
    const float* Wk    = (const float*)d_in[6];
    const float* Wv    = (const float*)d_in[7];
    const float* Wke   = (const float*)d_in[8];
    const float* Wve   = (const float*)d_in[9];
    const float* Wout  = (const float*)d_in[10];
    const float* gamma = (const float*)d_in[11];
    const float* beta  = (const float*)d_in[12];
    const float* W1    = (const float*)d_in[13];
    const float* b1    = (const float*)d_in[14];
    const float* W2    = (const float*)d_in[15];
    const float* b2    = (const float*)d_in[16];
    float* out = (float*)d_out;

    char* ws = (char*)d_ws;
    // workspace layout (bytes)
    float* qproj  = (float*)(ws + 0);              // 20000*128*4 = 10,240,000 ; reused as out0
    float* kproj  = (float*)(ws + 10240000);       //  5000*128*4 =  2,560,000
    float* vproj  = (float*)(ws + 12800000);       //  2,560,000
    float* agg    = (float*)(ws + 15360000);       // 10,240,000 ; reused as h1
    int*   sorted = (int*)  (ws + 25600000);       //  1,600,000
    int*   counts = (int*)  (ws + 27200000);       //     80,000
    int*   starts = (int*)  (ws + 27280128);       //     80,128
    int*   cursors= (int*)  (ws + 27360256);       //     80,000
    float* stats  = (float*)(ws + 27440384);       //      1,024
    float* bnp    = (float*)(ws + 27441408);       //      1,024

    float* out0 = qproj;  // reuse after attention
    float* h1   = agg;    // reuse after Wout gemm

    dim3 blk(256);

    // 1-3: projections
    gemm128<false,false><<<(N_RIGHTC + 63) / 64, blk, 0, stream>>>(right, Wq, nullptr, qproj, N_RIGHTC);
    gemm128<false,false><<<(N_LEFTC  + 63) / 64, blk, 0, stream>>>(left,  Wk, nullptr, kproj, N_LEFTC);
    gemm128<false,false><<<(N_LEFTC  + 63) / 64, blk, 0, stream>>>(left,  Wv, nullptr, vproj, N_LEFTC);

    // CSR build
    hipMemsetAsync(counts, 0, 80000, stream);
    hipMemsetAsync(stats, 0, 1024, stream);
    hist_kernel<<<1024, blk, 0, stream>>>(edst, counts);
    scan_kernel<<<1, blk, 0, stream>>>(counts, starts, cursors);
    scatter_kernel<<<1024, blk, 0, stream>>>(edst, cursors, sorted);

    // fused attention -> agg
    attn_kernel<<<N_RIGHTC, blk, 0, stream>>>(qproj, kproj, vproj, ef, esrc, sorted,
                                              starts, Wke, Wve, agg);

    // out0 = agg @ Wout   (overwrites qproj slot)
    gemm128<false,false><<<(N_RIGHTC + 63) / 64, blk, 0, stream>>>(agg, Wout, nullptr, out0, N_RIGHTC);

    // BN
    bn_stats<<<256, blk, 0, stream>>>(out0, stats);
    bn_finalize<<<1, dim3(128), 0, stream>>>(stats, gamma, beta, bnp);

    // h1 = relu([bn(out0), right] @ W1 + b1)   (overwrites agg slot)
    gemm_cat<<<(N_RIGHTC + 63) / 64, blk, 0, stream>>>(out0, right, bnp, W1, b1, h1, N_RIGHTC);

    // out = h1 @ W2 + b2
    gemm128<true,false><<<(N_RIGHTC + 63) / 64, blk, 0, stream>>>(h1, W2, b2, out, N_RIGHTC);
}

// Round 2
// 244.867 us; speedup vs baseline: 1.5007x; 1.5007x over previous
//
#include <hip/hip_runtime.h>
#include <math.h>

#define N_LEFTC  5000
#define N_RIGHTC 20000
#define NEDGE    400000

typedef __attribute__((ext_vector_type(8))) short bf16x8;
typedef __attribute__((ext_vector_type(4))) float f32x4;
typedef __attribute__((ext_vector_type(4))) unsigned short u16x4;

__device__ __forceinline__ unsigned short f2bf(float x) {
    unsigned int u = __float_as_uint(x);
    u = (u + 0x7fffu + ((u >> 16) & 1u)) >> 16;
    return (unsigned short)u;
}
__device__ __forceinline__ float bf2f(unsigned short u) {
    return __uint_as_float(((unsigned int)u) << 16);
}

// ---------------------------------------------------------------------------
// Cast right/left fp32 -> bf16 (vectorized float4 -> 4x bf16)
// ---------------------------------------------------------------------------
__global__ __launch_bounds__(256) void cast_inputs(const float* __restrict__ R,
                                                   unsigned short* __restrict__ Rb,
                                                   const float* __restrict__ L,
                                                   unsigned short* __restrict__ Lb)
{
    int i = blockIdx.x * 256 + threadIdx.x;
    const int n1 = N_RIGHTC * 128 / 4;   // 640000
    const int n2 = N_LEFTC * 128 / 4;    // 160000
    if (i < n1) {
        float4 v = ((const float4*)R)[i];
        u16x4 p = { f2bf(v.x), f2bf(v.y), f2bf(v.z), f2bf(v.w) };
        ((u16x4*)Rb)[i] = p;
    } else if (i < n1 + n2) {
        int j = i - n1;
        float4 v = ((const float4*)L)[j];
        u16x4 p = { f2bf(v.x), f2bf(v.y), f2bf(v.z), f2bf(v.w) };
        ((u16x4*)Lb)[j] = p;
    }
}

// ---------------------------------------------------------------------------
// Pack weights into MFMA B-fragment order (bf16).
// Bp[((ks*8+ct)*64+l)*8+j] = B[ks*32 + (l>>4)*8 + j][ct*16 + (l&15)]
// Layout: Wq@0, Wk@16384, Wv@32768, Wout@49152, W2@65536, W1@81920 (elements)
// ---------------------------------------------------------------------------
__global__ __launch_bounds__(256) void pack_weights(const float* __restrict__ Wq,
    const float* __restrict__ Wk, const float* __restrict__ Wv,
    const float* __restrict__ Wout, const float* __restrict__ W2,
    const float* __restrict__ W1, unsigned short* __restrict__ Bp)
{
    int i = blockIdx.x * 256 + threadIdx.x;
    if (i >= 5 * 16384 + 32768) return;
    const float* src; int rem;
    if (i < 81920) {
        int m = i >> 14; rem = i & 16383;
        src = (m == 0) ? Wq : (m == 1) ? Wk : (m == 2) ? Wv : (m == 3) ? Wout : W2;
    } else { rem = i - 81920; src = W1; }
    int j  = rem & 7;
    int l  = (rem >> 3) & 63;
    int ct = (rem >> 9) & 7;
    int ks = rem >> 12;
    int k  = ks * 32 + ((l >> 4) << 3) + j;
    int c  = (ct << 4) + (l & 15);
    Bp[i] = f2bf(src[k * 128 + c]);
}

// ---------------------------------------------------------------------------
// MFMA GEMM: C[M][128] = A[M][K] @ B[K][128], A bf16 row-major, Bp packed.
// 256 thr = 4 waves; wave w handles rows [bid*64+w*16, +16), all 128 cols.
// ---------------------------------------------------------------------------
template<int KS, bool OBF, bool BIAS>
__global__ __launch_bounds__(256) void gemm_mfma(const unsigned short* __restrict__ A,
    const unsigned short* __restrict__ Bp, const float* __restrict__ bias,
    void* __restrict__ Cv, int M)
{
    const int l  = threadIdx.x & 63;
    const int w  = threadIdx.x >> 6;
    const int r0 = blockIdx.x * 64 + w * 16;
    const int arow = r0 + (l & 15);
    const int kl = (l >> 4) * 8;
    f32x4 acc[8];
    #pragma unroll
    for (int ct = 0; ct < 8; ++ct) acc[ct] = (f32x4){0.f, 0.f, 0.f, 0.f};
    const bool aok = (arow < M);
    #pragma unroll
    for (int ks = 0; ks < KS; ++ks) {
        bf16x8 a = {0, 0, 0, 0, 0, 0, 0, 0};
        if (aok) a = *(const bf16x8*)(A + (size_t)arow * (KS * 32) + ks * 32 + kl);
        #pragma unroll
        for (int ct = 0; ct < 8; ++ct) {
            bf16x8 b = *(const bf16x8*)(Bp + (((ks * 8 + ct) * 64 + l) << 3));
            acc[ct] = __builtin_amdgcn_mfma_f32_16x16x32_bf16(a, b, acc[ct], 0, 0, 0);
        }
    }
    const int orow = r0 + (l >> 4) * 4;
    const int oc   = l & 15;
    #pragma unroll
    for (int ct = 0; ct < 8; ++ct) {
        int col = ct * 16 + oc;
        float bv = BIAS ? bias[col] : 0.f;
        #pragma unroll
        for (int r = 0; r < 4; ++r) {
            if (orow + r < M) {
                float v = acc[ct][r] + bv;
                if (OBF) ((unsigned short*)Cv)[(size_t)(orow + r) * 128 + col] = f2bf(v);
                else     ((float*)Cv)[(size_t)(orow + r) * 128 + col] = v;
            }
        }
    }
}

// ---------------------------------------------------------------------------
// Concat GEMM: h1 = relu([bn(out0), right] @ W1 + b1), bf16 in/out.
// ks<4 : A1 (out0_bf) with bn scale/shift applied in the fragment load.
// ks>=4: A2 (right_bf).
// ---------------------------------------------------------------------------
__global__ __launch_bounds__(256) void gemm_cat_mfma(const unsigned short* __restrict__ A1,
    const unsigned short* __restrict__ A2, const float* __restrict__ bnp,
    const unsigned short* __restrict__ Bp, const float* __restrict__ bias,
    unsigned short* __restrict__ C, int M)
{
    const int l  = threadIdx.x & 63;
    const int w  = threadIdx.x >> 6;
    const int r0 = blockIdx.x * 64 + w * 16;
    const int arow = r0 + (l & 15);
    const int kl = (l >> 4) * 8;
    f32x4 acc[8];
    #pragma unroll
    for (int ct = 0; ct < 8; ++ct) acc[ct] = (f32x4){0.f, 0.f, 0.f, 0.f};
    const bool aok = (arow < M);
    #pragma unroll
    for (int ks = 0; ks < 8; ++ks) {
        bf16x8 a = {0, 0, 0, 0, 0, 0, 0, 0};
        if (aok) {
            if (ks < 4) {
                int k0 = ks * 32 + kl;
                bf16x8 raw = *(const bf16x8*)(A1 + (size_t)arow * 128 + k0);
                float4 sc0 = *(const float4*)(bnp + k0);
                float4 sc1 = *(const float4*)(bnp + k0 + 4);
                float4 sh0 = *(const float4*)(bnp + 128 + k0);
                float4 sh1 = *(const float4*)(bnp + 128 + k0 + 4);
                float sc[8] = {sc0.x, sc0.y, sc0.z, sc0.w, sc1.x, sc1.y, sc1.z, sc1.w};
                float sh[8] = {sh0.x, sh0.y, sh0.z, sh0.w, sh1.x, sh1.y, sh1.z, sh1.w};
                #pragma unroll
                for (int j = 0; j < 8; ++j)
                    a[j] = (short)f2bf(bf2f((unsigned short)raw[j]) * sc[j] + sh[j]);
            } else {
                a = *(const bf16x8*)(A2 + (size_t)arow * 128 + (ks - 4) * 32 + kl);
            }
        }
        #pragma unroll
        for (int ct = 0; ct < 8; ++ct) {
            bf16x8 b = *(const bf16x8*)(Bp + (((ks * 8 + ct) * 64 + l) << 3));
            acc[ct] = __builtin_amdgcn_mfma_f32_16x16x32_bf16(a, b, acc[ct], 0, 0, 0);
        }
    }
    const int orow = r0 + (l >> 4) * 4;
    const int oc   = l & 15;
    #pragma unroll
    for (int ct = 0; ct < 8; ++ct) {
        int col = ct * 16 + oc;
        float bv = bias[col];
        #pragma unroll
        for (int r = 0; r < 4; ++r) {
            if (orow + r < M) {
                float v = fmaxf(acc[ct][r] + bv, 0.f);
                C[(size_t)(orow + r) * 128 + col] = f2bf(v);
            }
        }
    }
}

// ---------------------------------------------------------------------------
// CSR build: histogram -> scan -> scatter
// ---------------------------------------------------------------------------
__global__ void hist_kernel(const int* __restrict__ edst, int* __restrict__ counts)
{
    for (int i = blockIdx.x * blockDim.x + threadIdx.x; i < NEDGE; i += gridDim.x * blockDim.x)
        atomicAdd(&counts[edst[i]], 1);
}

__global__ __launch_bounds__(1024) void scan_kernel(const int* __restrict__ counts,
    int* __restrict__ starts, int* __restrict__ cursors)
{
    const int t = threadIdx.x;
    const int CH = 20;
    int lo = t * CH;
    int hi = lo + CH; if (hi > N_RIGHTC) hi = N_RIGHTC;
    int sum = 0;
    for (int i = lo; i < hi; ++i) sum += counts[i];
    int lane = t & 63, wv = t >> 6;
    int x = sum;
    #pragma unroll
    for (int o = 1; o < 64; o <<= 1) {
        int y = __shfl_up(x, o);
        if (lane >= o) x += y;
    }
    __shared__ int wsum[16], woff[16];
    if (lane == 63) wsum[wv] = x;
    __syncthreads();
    if (t == 0) {
        int run = 0;
        #pragma unroll
        for (int i = 0; i < 16; ++i) { woff[i] = run; run += wsum[i]; }
        starts[N_RIGHTC] = run;
    }
    __syncthreads();
    int run = x - sum + woff[wv];
    for (int i = lo; i < hi; ++i) {
        starts[i] = run; cursors[i] = run; run += counts[i];
    }
}

__global__ void scatter_kernel(const int* __restrict__ edst, int* __restrict__ cursors,
                               int* __restrict__ sorted)
{
    for (int i = blockIdx.x * blockDim.x + threadIdx.x; i < NEDGE; i += gridDim.x * blockDim.x) {
        int d = edst[i];
        int p = atomicAdd(&cursors[d], 1);
        sorted[p] = i;
    }
}

// ---------------------------------------------------------------------------
// Fused edge attention. One WAVE per dst node (4 waves/block).
// Within a wave: lanes 0-31 = edge stream 0, lanes 32-63 = edge stream 1.
// Each 4-lane quad owns one head's 16 dims (4 dims/lane).
// No max-subtraction (logits ~N(0,1); exp safe; math identical).
// ---------------------------------------------------------------------------
__global__ __launch_bounds__(256) void attn_kernel(
    const unsigned short* __restrict__ qp, const unsigned short* __restrict__ kp,
    const unsigned short* __restrict__ vp, const float* __restrict__ ef,
    const int* __restrict__ esrc, const int* __restrict__ sorted,
    const int* __restrict__ starts, const float* __restrict__ Wke,
    const float* __restrict__ Wve, unsigned short* __restrict__ agg)
{
    const int w    = threadIdx.x >> 6;
    const int l    = threadIdx.x & 63;
    const int d    = blockIdx.x * 4 + w;
    const int half = l >> 5;
    const int hl   = l & 31;
    const int c0   = hl * 4;            // 4 consecutive columns of one head

    // per-lane edge-projection weights (registers, no LDS)
    float wke[4][4], wve[4][4];
    #pragma unroll
    for (int f = 0; f < 4; ++f) {
        float4 a = *(const float4*)(Wke + f * 128 + c0);
        wke[f][0] = a.x; wke[f][1] = a.y; wke[f][2] = a.z; wke[f][3] = a.w;
        float4 b = *(const float4*)(Wve + f * 128 + c0);
        wve[f][0] = b.x; wve[f][1] = b.y; wve[f][2] = b.z; wve[f][3] = b.w;
    }
    u16x4 qu = *(const u16x4*)(qp + (size_t)d * 128 + c0);
    float qv[4] = { bf2f(qu[0]), bf2f(qu[1]), bf2f(qu[2]), bf2f(qu[3]) };

    const int e0 = starts[d], e1 = starts[d + 1];
    float s = 0.f;
    float av[4] = {0.f, 0.f, 0.f, 0.f};

    for (int i = e0 + half; i < e1; i += 2) {
        int eid = sorted[i];
        int src = esrc[eid];
        float4 f = *(const float4*)(ef + (size_t)eid * 4);
        u16x4 ku = *(const u16x4*)(kp + (size_t)src * 128 + c0);
        u16x4 vu = *(const u16x4*)(vp + (size_t)src * 128 + c0);
        float p = 0.f;
        float vve[4];
        #pragma unroll
        for (int j = 0; j < 4; ++j) {
            float ke = f.x * wke[0][j] + f.y * wke[1][j] + f.z * wke[2][j] + f.w * wke[3][j];
            float ve = f.x * wve[0][j] + f.y * wve[1][j] + f.z * wve[2][j] + f.w * wve[3][j];
            float kj = bf2f(ku[j]);
            float vj = bf2f(vu[j]);
            p += qv[j] * (kj + ke);
            vve[j] = vj + ve;
        }
        p += __shfl_xor(p, 1);
        p += __shfl_xor(p, 2);          // sum over the head's 4 lanes (16 dims)
        float e = __expf(p * 0.25f);    // 1/sqrt(16)
        s += e;
        #pragma unroll
        for (int j = 0; j < 4; ++j) av[j] += e * vve[j];
    }
    // merge the two 32-lane streams
    s += __shfl_xor(s, 32);
    #pragma unroll
    for (int j = 0; j < 4; ++j) av[j] += __shfl_xor(av[j], 32);
    if (half == 0) {
        float inv = 1.f / (s + 1e-16f);
        u16x4 o = { f2bf(av[0] * inv), f2bf(av[1] * inv), f2bf(av[2] * inv), f2bf(av[3] * inv) };
        *(u16x4*)(agg + (size_t)d * 128 + c0) = o;
    }
}

// ---------------------------------------------------------------------------
// BatchNorm stats (from bf16 out0) + finalize
// ---------------------------------------------------------------------------
__global__ __launch_bounds__(256) void bn_stats(const unsigned short* __restrict__ X,
                                                float* __restrict__ stats)
{
    const int col = threadIdx.x & 127;
    const int rg  = threadIdx.x >> 7;
    float s = 0.f, q = 0.f;
    for (int r = blockIdx.x * 2 + rg; r < N_RIGHTC; r += gridDim.x * 2) {
        float v = bf2f(X[(size_t)r * 128 + col]);
        s += v; q += v * v;
    }
    __shared__ float ls[256], lq[256];
    ls[threadIdx.x] = s; lq[threadIdx.x] = q;
    __syncthreads();
    if (rg == 0) {
        atomicAdd(&stats[col],       ls[col] + ls[128 + col]);
        atomicAdd(&stats[128 + col], lq[col] + lq[128 + col]);
    }
}

__global__ void bn_finalize(const float* __restrict__ stats, const float* __restrict__ gamma,
                            const float* __restrict__ beta, float* __restrict__ bnp)
{
    int c = threadIdx.x;
    float mean = stats[c] * (1.f / N_RIGHTC);
    float var  = stats[128 + c] * (1.f / N_RIGHTC) - mean * mean;
    float sc   = gamma[c] * rsqrtf(var + 1e-5f);
    bnp[c]       = sc;
    bnp[128 + c] = beta[c] - mean * sc;
}

// ---------------------------------------------------------------------------
// launch
// ---------------------------------------------------------------------------
extern "C" void kernel_launch(void* const* d_in, const int* in_sizes, int n_in,
                              void* d_out, int out_size, void* d_ws, size_t ws_size,
                              hipStream_t stream)
{
    const float* left  = (const float*)d_in[0];
    const float* right = (const float*)d_in[1];
    const float* ef    = (const float*)d_in[2];
    const int*   esrc  = (const int*)d_in[3];
    const int*   edst  = (const int*)d_in[4];
    const float* Wq    = (const float*)d_in[5];
    const float* Wk    = (const float*)d_in[6];
    const float* Wv    = (const float*)d_in[7];
    const float* Wke   = (const float*)d_in[8];
    const float* Wve   = (const float*)d_in[9];
    const float* Wout  = (const float*)d_in[10];
    const float* gamma = (const float*)d_in[11];
    const float* beta  = (const float*)d_in[12];
    const float* W1    = (const float*)d_in[13];
    const float* b1    = (const float*)d_in[14];
    const float* W2    = (const float*)d_in[15];
    const float* b2    = (const float*)d_in[16];
    float* out = (float*)d_out;

    char* ws = (char*)d_ws;
    unsigned short* right_bf = (unsigned short*)(ws + 0);          // 5,120,000
    unsigned short* left_bf  = (unsigned short*)(ws + 5120000);    // 1,280,000
    unsigned short* qproj    = (unsigned short*)(ws + 6400000);    // 5,120,000
    unsigned short* kproj    = (unsigned short*)(ws + 11520000);   // 1,280,000
    unsigned short* vproj    = (unsigned short*)(ws + 12800000);   // 1,280,000
    unsigned short* agg      = (unsigned short*)(ws + 14080000);   // 5,120,000 (reused as h1)
    unsigned short* out0     = (unsigned short*)(ws + 19200000);   // 5,120,000
    int*   sorted  = (int*)(ws + 24320000);                        // 1,600,000
    int*   counts  = (int*)(ws + 25920000);                        //    80,000
    int*   starts  = (int*)(ws + 26000000);                        //    80,128
    int*   cursors = (int*)(ws + 26080128);                        //    80,000
    float* stats   = (float*)(ws + 26160128);                      //     1,024
    float* bnp     = (float*)(ws + 26161152);                      //     1,024
    unsigned short* Bp = (unsigned short*)(ws + 26162176);         //   229,376  -> total 26.4 MB
    unsigned short* h1 = agg;

    hipMemsetAsync(counts, 0, 80000, stream);
    hipMemsetAsync(stats, 0, 1024, stream);

    cast_inputs<<<3125, 256, 0, stream>>>(right, right_bf, left, left_bf);
    pack_weights<<<448, 256, 0, stream>>>(Wq, Wk, Wv, Wout, W2, W1, Bp);

    hist_kernel<<<512, 256, 0, stream>>>(edst, counts);
    scan_kernel<<<1, 1024, 0, stream>>>(counts, starts, cursors);
    scatter_kernel<<<512, 256, 0, stream>>>(edst, cursors, sorted);

    gemm_mfma<4, true, false><<<(N_RIGHTC + 63) / 64, 256, 0, stream>>>(right_bf, Bp,         nullptr, qproj, N_RIGHTC);
    gemm_mfma<4, true, false><<<(N_LEFTC  + 63) / 64, 256, 0, stream>>>(left_bf,  Bp + 16384, nullptr, kproj, N_LEFTC);
    gemm_mfma<4, true, false><<<(N_LEFTC  + 63) / 64, 256, 0, stream>>>(left_bf,  Bp + 32768, nullptr, vproj, N_LEFTC);

    attn_kernel<<<N_RIGHTC / 4, 256, 0, stream>>>(qproj, kproj, vproj, ef, esrc, sorted,
                                                  starts, Wke, Wve, agg);

    gemm_mfma<4, true, false><<<(N_RIGHTC + 63) / 64, 256, 0, stream>>>(agg, Bp + 49152, nullptr, out0, N_RIGHTC);

    bn_stats<<<256, 256, 0, stream>>>(out0, stats);
    bn_finalize<<<1, dim3(128), 0, stream>>>(stats, gamma, beta, bnp);

    gemm_cat_mfma<<<(N_RIGHTC + 63) / 64, 256, 0, stream>>>(out0, right_bf, bnp, Bp + 81920, b1, h1, N_RIGHTC);

    gemm_mfma<4, false, true><<<(N_RIGHTC + 63) / 64, 256, 0, stream>>>(h1, Bp + 65536, b2, out, N_RIGHTC);
}

// Round 3
// 213.538 us; speedup vs baseline: 1.7208x; 1.1467x over previous
//
#include <hip/hip_runtime.h>
#include <math.h>

#define N_LEFTC  5000
#define N_RIGHTC 20000
#define NEDGE    400000

typedef __attribute__((ext_vector_type(8))) short bf16x8;
typedef __attribute__((ext_vector_type(4))) float f32x4;
typedef __attribute__((ext_vector_type(4))) unsigned short u16x4;

__device__ __forceinline__ unsigned short f2bf(float x) {
    unsigned int u = __float_as_uint(x);
    u = (u + 0x7fffu + ((u >> 16) & 1u)) >> 16;
    return (unsigned short)u;
}
__device__ __forceinline__ float bf2f(unsigned short u) {
    return __uint_as_float(((unsigned int)u) << 16);
}

// ---------------------------------------------------------------------------
// Pack weights into MFMA B-fragment order (bf16).
// Bp[((ks*8+ct)*64+l)*8+j] = B[ks*32 + (l>>4)*8 + j][ct*16 + (l&15)]
// Layout: Wq@0, Wk@16384, Wv@32768, Wout@49152, W2@65536, W1@81920 (elements)
// ---------------------------------------------------------------------------
__global__ __launch_bounds__(256) void pack_weights(const float* __restrict__ Wq,
    const float* __restrict__ Wk, const float* __restrict__ Wv,
    const float* __restrict__ Wout, const float* __restrict__ W2,
    const float* __restrict__ W1, unsigned short* __restrict__ Bp)
{
    int i = blockIdx.x * 256 + threadIdx.x;
    if (i >= 5 * 16384 + 32768) return;
    const float* src; int rem;
    if (i < 81920) {
        int m = i >> 14; rem = i & 16383;
        src = (m == 0) ? Wq : (m == 1) ? Wk : (m == 2) ? Wv : (m == 3) ? Wout : W2;
    } else { rem = i - 81920; src = W1; }
    int j  = rem & 7;
    int l  = (rem >> 3) & 63;
    int ct = (rem >> 9) & 7;
    int ks = rem >> 12;
    int k  = ks * 32 + ((l >> 4) << 3) + j;
    int c  = (ct << 4) + (l & 15);
    Bp[i] = f2bf(src[k * 128 + c]);
}

// ---------------------------------------------------------------------------
// Load one bf16 A-fragment (8 elems) from fp32 or bf16 row-major A
// ---------------------------------------------------------------------------
__device__ __forceinline__ bf16x8 loadA_f32(const float* p) {
    float4 f0 = *(const float4*)p;
    float4 f1 = *(const float4*)(p + 4);
    bf16x8 a;
    a[0] = (short)f2bf(f0.x); a[1] = (short)f2bf(f0.y);
    a[2] = (short)f2bf(f0.z); a[3] = (short)f2bf(f0.w);
    a[4] = (short)f2bf(f1.x); a[5] = (short)f2bf(f1.y);
    a[6] = (short)f2bf(f1.z); a[7] = (short)f2bf(f1.w);
    return a;
}

// ---------------------------------------------------------------------------
// MFMA GEMM: C[M][128] = A[M][128] @ B, A fp32 or bf16 row-major, Bp packed.
// 256 thr = 4 waves; wave w handles rows [bid*64+w*16, +16), all 128 cols.
// ---------------------------------------------------------------------------
template<bool ABF, bool OBF>
__global__ __launch_bounds__(256) void gemm_mfma(const void* __restrict__ Av,
    const unsigned short* __restrict__ Bp, void* __restrict__ Cv, int M)
{
    const int l  = threadIdx.x & 63;
    const int w  = threadIdx.x >> 6;
    const int r0 = blockIdx.x * 64 + w * 16;
    const int arow = r0 + (l & 15);
    const int kl = (l >> 4) * 8;
    f32x4 acc[8];
    #pragma unroll
    for (int ct = 0; ct < 8; ++ct) acc[ct] = (f32x4){0.f, 0.f, 0.f, 0.f};
    const bool aok = (arow < M);
    #pragma unroll
    for (int ks = 0; ks < 4; ++ks) {
        bf16x8 a = {0, 0, 0, 0, 0, 0, 0, 0};
        if (aok) {
            if (ABF) a = *(const bf16x8*)((const unsigned short*)Av + (size_t)arow * 128 + ks * 32 + kl);
            else     a = loadA_f32((const float*)Av + (size_t)arow * 128 + ks * 32 + kl);
        }
        #pragma unroll
        for (int ct = 0; ct < 8; ++ct) {
            bf16x8 b = *(const bf16x8*)(Bp + (((ks * 8 + ct) * 64 + l) << 3));
            acc[ct] = __builtin_amdgcn_mfma_f32_16x16x32_bf16(a, b, acc[ct], 0, 0, 0);
        }
    }
    const int orow = r0 + (l >> 4) * 4;
    const int oc   = l & 15;
    #pragma unroll
    for (int ct = 0; ct < 8; ++ct) {
        int col = ct * 16 + oc;
        #pragma unroll
        for (int r = 0; r < 4; ++r) {
            if (orow + r < M) {
                float v = acc[ct][r];
                if (OBF) ((unsigned short*)Cv)[(size_t)(orow + r) * 128 + col] = f2bf(v);
                else     ((float*)Cv)[(size_t)(orow + r) * 128 + col] = v;
            }
        }
    }
}

// ---------------------------------------------------------------------------
// Fused K+V projection: A (fp32) read once, two packed B mats, two outputs.
// ---------------------------------------------------------------------------
__global__ __launch_bounds__(256) void gemm_kv(const float* __restrict__ A,
    const unsigned short* __restrict__ BpK, const unsigned short* __restrict__ BpV,
    unsigned short* __restrict__ K, unsigned short* __restrict__ V, int M)
{
    const int l  = threadIdx.x & 63;
    const int w  = threadIdx.x >> 6;
    const int r0 = blockIdx.x * 64 + w * 16;
    const int arow = r0 + (l & 15);
    const int kl = (l >> 4) * 8;
    f32x4 acck[8], accv[8];
    #pragma unroll
    for (int ct = 0; ct < 8; ++ct) { acck[ct] = (f32x4){0,0,0,0}; accv[ct] = (f32x4){0,0,0,0}; }
    const bool aok = (arow < M);
    #pragma unroll
    for (int ks = 0; ks < 4; ++ks) {
        bf16x8 a = {0, 0, 0, 0, 0, 0, 0, 0};
        if (aok) a = loadA_f32(A + (size_t)arow * 128 + ks * 32 + kl);
        #pragma unroll
        for (int ct = 0; ct < 8; ++ct) {
            int fo = ((ks * 8 + ct) * 64 + l) << 3;
            bf16x8 bk = *(const bf16x8*)(BpK + fo);
            bf16x8 bv = *(const bf16x8*)(BpV + fo);
            acck[ct] = __builtin_amdgcn_mfma_f32_16x16x32_bf16(a, bk, acck[ct], 0, 0, 0);
            accv[ct] = __builtin_amdgcn_mfma_f32_16x16x32_bf16(a, bv, accv[ct], 0, 0, 0);
        }
    }
    const int orow = r0 + (l >> 4) * 4;
    const int oc   = l & 15;
    #pragma unroll
    for (int ct = 0; ct < 8; ++ct) {
        int col = ct * 16 + oc;
        #pragma unroll
        for (int r = 0; r < 4; ++r) {
            if (orow + r < M) {
                K[(size_t)(orow + r) * 128 + col] = f2bf(acck[ct][r]);
                V[(size_t)(orow + r) * 128 + col] = f2bf(accv[ct][r]);
            }
        }
    }
}

// ---------------------------------------------------------------------------
// Wout GEMM (agg bf16 -> out0 bf16) with fused BN statistics (sum, sumsq)
// ---------------------------------------------------------------------------
__global__ __launch_bounds__(256) void gemm_out0(const unsigned short* __restrict__ A,
    const unsigned short* __restrict__ Bp, unsigned short* __restrict__ C,
    float* __restrict__ stats, int M)
{
    __shared__ float sds[256];
    if (threadIdx.x < 256) sds[threadIdx.x] = 0.f;
    __syncthreads();

    const int l  = threadIdx.x & 63;
    const int w  = threadIdx.x >> 6;
    const int r0 = blockIdx.x * 64 + w * 16;
    const int arow = r0 + (l & 15);
    const int kl = (l >> 4) * 8;
    f32x4 acc[8];
    #pragma unroll
    for (int ct = 0; ct < 8; ++ct) acc[ct] = (f32x4){0.f, 0.f, 0.f, 0.f};
    const bool aok = (arow < M);
    #pragma unroll
    for (int ks = 0; ks < 4; ++ks) {
        bf16x8 a = {0, 0, 0, 0, 0, 0, 0, 0};
        if (aok) a = *(const bf16x8*)(A + (size_t)arow * 128 + ks * 32 + kl);
        #pragma unroll
        for (int ct = 0; ct < 8; ++ct) {
            bf16x8 b = *(const bf16x8*)(Bp + (((ks * 8 + ct) * 64 + l) << 3));
            acc[ct] = __builtin_amdgcn_mfma_f32_16x16x32_bf16(a, b, acc[ct], 0, 0, 0);
        }
    }
    const int orow = r0 + (l >> 4) * 4;
    const int oc   = l & 15;
    #pragma unroll
    for (int ct = 0; ct < 8; ++ct) {
        int col = ct * 16 + oc;
        float cs = 0.f, cq = 0.f;
        #pragma unroll
        for (int r = 0; r < 4; ++r) {
            if (orow + r < M) {
                float v = acc[ct][r];
                C[(size_t)(orow + r) * 128 + col] = f2bf(v);
                cs += v; cq += v * v;
            }
        }
        atomicAdd(&sds[col], cs);
        atomicAdd(&sds[128 + col], cq);
    }
    __syncthreads();
    if (threadIdx.x < 256) atomicAdd(&stats[threadIdx.x], sds[threadIdx.x]);
}

__global__ void bn_finalize(const float* __restrict__ stats, const float* __restrict__ gamma,
                            const float* __restrict__ beta, float* __restrict__ bnp)
{
    int c = threadIdx.x;
    float mean = stats[c] * (1.f / N_RIGHTC);
    float var  = stats[128 + c] * (1.f / N_RIGHTC) - mean * mean;
    float sc   = gamma[c] * rsqrtf(var + 1e-5f);
    bnp[c]       = sc;
    bnp[128 + c] = beta[c] - mean * sc;
}

// ---------------------------------------------------------------------------
// Fused tail: h = relu([bn(out0), right] @ W1 + b1) ; out = h @ W2 + b2
// Stage 1 accumulates K=256, epilogue -> LDS bf16 tile (64 x 132+pad),
// stage 2 reads A-fragments from LDS, writes fp32 d_out.
// ---------------------------------------------------------------------------
__global__ __launch_bounds__(256) void gemm_tail(const unsigned short* __restrict__ A1,
    const float* __restrict__ A2, const float* __restrict__ bnp,
    const unsigned short* __restrict__ Bp1, const float* __restrict__ b1,
    const unsigned short* __restrict__ Bp2, const float* __restrict__ b2,
    float* __restrict__ out, int M)
{
    __shared__ unsigned short h[64][136];   // 272B row stride: 16B-aligned, bank-spread
    const int l  = threadIdx.x & 63;
    const int w  = threadIdx.x >> 6;
    const int r0 = blockIdx.x * 64 + w * 16;
    const int arow = r0 + (l & 15);
    const int kl = (l >> 4) * 8;
    f32x4 acc[8];
    #pragma unroll
    for (int ct = 0; ct < 8; ++ct) acc[ct] = (f32x4){0.f, 0.f, 0.f, 0.f};
    const bool aok = (arow < M);
    #pragma unroll
    for (int ks = 0; ks < 8; ++ks) {
        bf16x8 a = {0, 0, 0, 0, 0, 0, 0, 0};
        if (aok) {
            if (ks < 4) {
                int k0 = ks * 32 + kl;
                bf16x8 raw = *(const bf16x8*)(A1 + (size_t)arow * 128 + k0);
                float4 sc0 = *(const float4*)(bnp + k0);
                float4 sc1 = *(const float4*)(bnp + k0 + 4);
                float4 sh0 = *(const float4*)(bnp + 128 + k0);
                float4 sh1 = *(const float4*)(bnp + 128 + k0 + 4);
                float sc[8] = {sc0.x, sc0.y, sc0.z, sc0.w, sc1.x, sc1.y, sc1.z, sc1.w};
                float sh[8] = {sh0.x, sh0.y, sh0.z, sh0.w, sh1.x, sh1.y, sh1.z, sh1.w};
                #pragma unroll
                for (int j = 0; j < 8; ++j)
                    a[j] = (short)f2bf(bf2f((unsigned short)raw[j]) * sc[j] + sh[j]);
            } else {
                a = loadA_f32(A2 + (size_t)arow * 128 + (ks - 4) * 32 + kl);
            }
        }
        #pragma unroll
        for (int ct = 0; ct < 8; ++ct) {
            bf16x8 b = *(const bf16x8*)(Bp1 + (((ks * 8 + ct) * 64 + l) << 3));
            acc[ct] = __builtin_amdgcn_mfma_f32_16x16x32_bf16(a, b, acc[ct], 0, 0, 0);
        }
    }
    // stage-1 epilogue -> LDS (bias + relu + bf16)
    {
        const int lr0 = w * 16 + (l >> 4) * 4;
        const int oc  = l & 15;
        #pragma unroll
        for (int ct = 0; ct < 8; ++ct) {
            int col = ct * 16 + oc;
            float bv = b1[col];
            #pragma unroll
            for (int r = 0; r < 4; ++r)
                h[lr0 + r][col] = f2bf(fmaxf(acc[ct][r] + bv, 0.f));
        }
    }
    __syncthreads();
    // stage 2: rows w*16.., A-fragments from LDS
    #pragma unroll
    for (int ct = 0; ct < 8; ++ct) acc[ct] = (f32x4){0.f, 0.f, 0.f, 0.f};
    const int lrow = w * 16 + (l & 15);
    #pragma unroll
    for (int ks = 0; ks < 4; ++ks) {
        bf16x8 a = *(const bf16x8*)&h[lrow][ks * 32 + kl];
        #pragma unroll
        for (int ct = 0; ct < 8; ++ct) {
            bf16x8 b = *(const bf16x8*)(Bp2 + (((ks * 8 + ct) * 64 + l) << 3));
            acc[ct] = __builtin_amdgcn_mfma_f32_16x16x32_bf16(a, b, acc[ct], 0, 0, 0);
        }
    }
    const int orow = r0 + (l >> 4) * 4;
    const int oc   = l & 15;
    #pragma unroll
    for (int ct = 0; ct < 8; ++ct) {
        int col = ct * 16 + oc;
        float bv = b2[col];
        #pragma unroll
        for (int r = 0; r < 4; ++r)
            if (orow + r < M)
                out[(size_t)(orow + r) * 128 + col] = acc[ct][r] + bv;
    }
}

// ---------------------------------------------------------------------------
// CSR build: histogram -> scan -> scatter (with src/ef pre-gather)
// ---------------------------------------------------------------------------
__global__ void hist_kernel(const int* __restrict__ edst, int* __restrict__ counts)
{
    for (int i = blockIdx.x * blockDim.x + threadIdx.x; i < NEDGE; i += gridDim.x * blockDim.x)
        atomicAdd(&counts[edst[i]], 1);
}

__global__ __launch_bounds__(1024) void scan_kernel(const int* __restrict__ counts,
    int* __restrict__ starts, int* __restrict__ cursors)
{
    const int t = threadIdx.x;
    const int CH = 20;
    int lo = t * CH;
    int hi = lo + CH; if (hi > N_RIGHTC) hi = N_RIGHTC;
    int sum = 0;
    for (int i = lo; i < hi; ++i) sum += counts[i];
    int lane = t & 63, wv = t >> 6;
    int x = sum;
    #pragma unroll
    for (int o = 1; o < 64; o <<= 1) {
        int y = __shfl_up(x, o);
        if (lane >= o) x += y;
    }
    __shared__ int wsum[16], woff[16];
    if (lane == 63) wsum[wv] = x;
    __syncthreads();
    if (t == 0) {
        int run = 0;
        #pragma unroll
        for (int i = 0; i < 16; ++i) { woff[i] = run; run += wsum[i]; }
        starts[N_RIGHTC] = run;
    }
    __syncthreads();
    int run = x - sum + woff[wv];
    for (int i = lo; i < hi; ++i) {
        starts[i] = run; cursors[i] = run; run += counts[i];
    }
}

__global__ void scatter_kernel(const int* __restrict__ edst, const int* __restrict__ esrc,
                               const float4* __restrict__ ef, int* __restrict__ cursors,
                               int* __restrict__ srcs, float4* __restrict__ efs)
{
    for (int i = blockIdx.x * blockDim.x + threadIdx.x; i < NEDGE; i += gridDim.x * blockDim.x) {
        int d = edst[i];
        int p = atomicAdd(&cursors[d], 1);
        srcs[p] = esrc[i];
        efs[p]  = ef[i];
    }
}

// ---------------------------------------------------------------------------
// Fused edge attention. One WAVE per dst (4 waves/block).
// Halves of the wave take [e0,mid) and [mid,e1); 4 edges batched per iter
// (8 independent gather chains in flight per wave).
// Each 4-lane quad owns one head's 16 dims (4 dims/lane).
// ---------------------------------------------------------------------------
__global__ __launch_bounds__(256) void attn_kernel(
    const unsigned short* __restrict__ qp, const unsigned short* __restrict__ kp,
    const unsigned short* __restrict__ vp, const float4* __restrict__ efs,
    const int* __restrict__ srcs, const int* __restrict__ starts,
    const float* __restrict__ Wke, const float* __restrict__ Wve,
    unsigned short* __restrict__ agg)
{
    const int w    = threadIdx.x >> 6;
    const int l    = threadIdx.x & 63;
    const int d    = blockIdx.x * 4 + w;
    const int half = l >> 5;
    const int hl   = l & 31;
    const int c0   = hl * 4;

    float wke[4][4], wve[4][4];
    #pragma unroll
    for (int f = 0; f < 4; ++f) {
        float4 a = *(const float4*)(Wke + f * 128 + c0);
        wke[f][0] = a.x; wke[f][1] = a.y; wke[f][2] = a.z; wke[f][3] = a.w;
        float4 b = *(const float4*)(Wve + f * 128 + c0);
        wve[f][0] = b.x; wve[f][1] = b.y; wve[f][2] = b.z; wve[f][3] = b.w;
    }
    u16x4 qu = *(const u16x4*)(qp + (size_t)d * 128 + c0);
    float qv[4] = { bf2f(qu[0]), bf2f(qu[1]), bf2f(qu[2]), bf2f(qu[3]) };

    const int e0 = starts[d], e1 = starts[d + 1];
    const int mid = (e0 + e1 + 1) >> 1;
    const int p0 = half ? mid : e0;
    const int pe = half ? e1 : mid;

    float s = 0.f;
    float av[4] = {0.f, 0.f, 0.f, 0.f};

    for (int p = p0; p < pe; p += 4) {
        int src_[4]; float4 ef_[4]; bool ok_[4];
        #pragma unroll
        for (int b = 0; b < 4; ++b) {
            int idx = p + b;
            ok_[b] = (idx < pe);
            int ii = ok_[b] ? idx : p0;
            src_[b] = srcs[ii];
            ef_[b]  = efs[ii];
        }
        u16x4 ku_[4], vu_[4];
        #pragma unroll
        for (int b = 0; b < 4; ++b) {
            ku_[b] = *(const u16x4*)(kp + (size_t)src_[b] * 128 + c0);
            vu_[b] = *(const u16x4*)(vp + (size_t)src_[b] * 128 + c0);
        }
        #pragma unroll
        for (int b = 0; b < 4; ++b) {
            float4 f = ef_[b];
            float pp = 0.f;
            float vve[4];
            #pragma unroll
            for (int j = 0; j < 4; ++j) {
                float ke = f.x * wke[0][j] + f.y * wke[1][j] + f.z * wke[2][j] + f.w * wke[3][j];
                float ve = f.x * wve[0][j] + f.y * wve[1][j] + f.z * wve[2][j] + f.w * wve[3][j];
                pp += qv[j] * (bf2f(ku_[b][j]) + ke);
                vve[j] = bf2f(vu_[b][j]) + ve;
            }
            pp += __shfl_xor(pp, 1);
            pp += __shfl_xor(pp, 2);           // 16-dim dot done within the quad
            float e = ok_[b] ? __expf(pp * 0.25f) : 0.f;
            s += e;
            #pragma unroll
            for (int j = 0; j < 4; ++j) av[j] += e * vve[j];
        }
    }
    s += __shfl_xor(s, 32);
    #pragma unroll
    for (int j = 0; j < 4; ++j) av[j] += __shfl_xor(av[j], 32);
    if (half == 0) {
        float inv = 1.f / (s + 1e-16f);
        u16x4 o = { f2bf(av[0] * inv), f2bf(av[1] * inv), f2bf(av[2] * inv), f2bf(av[3] * inv) };
        *(u16x4*)(agg + (size_t)d * 128 + c0) = o;
    }
}

// ---------------------------------------------------------------------------
// launch
// ---------------------------------------------------------------------------
extern "C" void kernel_launch(void* const* d_in, const int* in_sizes, int n_in,
                              void* d_out, int out_size, void* d_ws, size_t ws_size,
                              hipStream_t stream)
{
    const float* left  = (const float*)d_in[0];
    const float* right = (const float*)d_in[1];
    const float* ef    = (const float*)d_in[2];
    const int*   esrc  = (const int*)d_in[3];
    const int*   edst  = (const int*)d_in[4];
    const float* Wq    = (const float*)d_in[5];
    const float* Wk    = (const float*)d_in[6];
    const float* Wv    = (const float*)d_in[7];
    const float* Wke   = (const float*)d_in[8];
    const float* Wve   = (const float*)d_in[9];
    const float* Wout  = (const float*)d_in[10];
    const float* gamma = (const float*)d_in[11];
    const float* beta  = (const float*)d_in[12];
    const float* W1    = (const float*)d_in[13];
    const float* b1    = (const float*)d_in[14];
    const float* W2    = (const float*)d_in[15];
    const float* b2    = (const float*)d_in[16];
    float* out = (float*)d_out;

    char* ws = (char*)d_ws;
    unsigned short* qproj = (unsigned short*)(ws + 0);          //  5,120,000
    unsigned short* kproj = (unsigned short*)(ws + 5120000);    //  1,280,000
    unsigned short* vproj = (unsigned short*)(ws + 6400000);    //  1,280,000
    unsigned short* agg   = (unsigned short*)(ws + 7680000);    //  5,120,000
    unsigned short* out0  = (unsigned short*)(ws + 12800000);   //  5,120,000
    int*    srcs   = (int*)   (ws + 17920000);                  //  1,600,000
    float4* efs    = (float4*)(ws + 19520000);                  //  6,400,000
    int*   counts  = (int*)(ws + 25920000);                     //     80,000
    int*   starts  = (int*)(ws + 26000000);                     //     80,128
    int*   cursors = (int*)(ws + 26080128);                     //     80,000
    float* stats   = (float*)(ws + 26160128);                   //      1,024
    float* bnp     = (float*)(ws + 26161152);                   //      1,024
    unsigned short* Bp = (unsigned short*)(ws + 26162176);      //    229,376

    hipMemsetAsync(counts, 0, 80000, stream);
    hipMemsetAsync(stats, 0, 1024, stream);

    pack_weights<<<448, 256, 0, stream>>>(Wq, Wk, Wv, Wout, W2, W1, Bp);

    hist_kernel<<<512, 256, 0, stream>>>(edst, counts);
    scan_kernel<<<1, 1024, 0, stream>>>(counts, starts, cursors);
    scatter_kernel<<<512, 256, 0, stream>>>(edst, esrc, (const float4*)ef, cursors, srcs, efs);

    gemm_mfma<false, true><<<(N_RIGHTC + 63) / 64, 256, 0, stream>>>(right, Bp, qproj, N_RIGHTC);
    gemm_kv<<<(N_LEFTC + 63) / 64, 256, 0, stream>>>(left, Bp + 16384, Bp + 32768, kproj, vproj, N_LEFTC);

    attn_kernel<<<N_RIGHTC / 4, 256, 0, stream>>>(qproj, kproj, vproj, efs, srcs,
                                                  starts, Wke, Wve, agg);

    gemm_out0<<<(N_RIGHTC + 63) / 64, 256, 0, stream>>>(agg, Bp + 49152, out0, stats, N_RIGHTC);
    bn_finalize<<<1, dim3(128), 0, stream>>>(stats, gamma, beta, bnp);

    gemm_tail<<<(N_RIGHTC + 63) / 64, 256, 0, stream>>>(out0, right, bnp, Bp + 81920, b1,
                                                        Bp + 65536, b2, out, N_RIGHTC);
}

// Round 4
// 180.649 us; speedup vs baseline: 2.0341x; 1.1821x over previous
//
#include <hip/hip_runtime.h>
#include <math.h>

#define N_LEFTC  5000
#define N_RIGHTC 20000
#define NEDGE    400000

typedef __attribute__((ext_vector_type(8))) short bf16x8;
typedef __attribute__((ext_vector_type(4))) float f32x4;
typedef __attribute__((ext_vector_type(4))) unsigned short u16x4;

__device__ __forceinline__ unsigned short f2bf(float x) {
    unsigned int u = __float_as_uint(x);
    u = (u + 0x7fffu + ((u >> 16) & 1u)) >> 16;
    return (unsigned short)u;
}
__device__ __forceinline__ float bf2f(unsigned short u) {
    return __uint_as_float(((unsigned int)u) << 16);
}

// ---------------------------------------------------------------------------
// bf16 A-fragment (8 elems) from fp32 row-major A
// ---------------------------------------------------------------------------
__device__ __forceinline__ bf16x8 loadA_f32(const float* p) {
    float4 f0 = *(const float4*)p;
    float4 f1 = *(const float4*)(p + 4);
    bf16x8 a;
    a[0] = (short)f2bf(f0.x); a[1] = (short)f2bf(f0.y);
    a[2] = (short)f2bf(f0.z); a[3] = (short)f2bf(f0.w);
    a[4] = (short)f2bf(f1.x); a[5] = (short)f2bf(f1.y);
    a[6] = (short)f2bf(f1.z); a[7] = (short)f2bf(f1.w);
    return a;
}

// ---------------------------------------------------------------------------
// Device GEMM body: C[64 rows @ bid][128] = A @ B (Bp packed fragments)
// ---------------------------------------------------------------------------
template<bool ABF, bool OBF>
__device__ __forceinline__ void gemm_body(const void* __restrict__ Av,
    const unsigned short* __restrict__ Bp, void* __restrict__ Cv, int M,
    int bid, int tid)
{
    const int l  = tid & 63;
    const int w  = tid >> 6;
    const int r0 = bid * 64 + w * 16;
    const int arow = r0 + (l & 15);
    const int kl = (l >> 4) * 8;
    f32x4 acc[8];
    #pragma unroll
    for (int ct = 0; ct < 8; ++ct) acc[ct] = (f32x4){0.f, 0.f, 0.f, 0.f};
    const bool aok = (arow < M);
    #pragma unroll
    for (int ks = 0; ks < 4; ++ks) {
        bf16x8 a = {0, 0, 0, 0, 0, 0, 0, 0};
        if (aok) {
            if (ABF) a = *(const bf16x8*)((const unsigned short*)Av + (size_t)arow * 128 + ks * 32 + kl);
            else     a = loadA_f32((const float*)Av + (size_t)arow * 128 + ks * 32 + kl);
        }
        #pragma unroll
        for (int ct = 0; ct < 8; ++ct) {
            bf16x8 b = *(const bf16x8*)(Bp + (((ks * 8 + ct) * 64 + l) << 3));
            acc[ct] = __builtin_amdgcn_mfma_f32_16x16x32_bf16(a, b, acc[ct], 0, 0, 0);
        }
    }
    const int orow = r0 + (l >> 4) * 4;
    const int oc   = l & 15;
    #pragma unroll
    for (int ct = 0; ct < 8; ++ct) {
        int col = ct * 16 + oc;
        #pragma unroll
        for (int r = 0; r < 4; ++r) {
            if (orow + r < M) {
                float v = acc[ct][r];
                if (OBF) ((unsigned short*)Cv)[(size_t)(orow + r) * 128 + col] = f2bf(v);
                else     ((float*)Cv)[(size_t)(orow + r) * 128 + col] = v;
            }
        }
    }
}

// ---------------------------------------------------------------------------
// Fused: pack_weights (blocks 0..447) + edge histogram (blocks 448..959)
// ---------------------------------------------------------------------------
__global__ __launch_bounds__(256) void pack_hist(const float* __restrict__ Wq,
    const float* __restrict__ Wk, const float* __restrict__ Wv,
    const float* __restrict__ Wout, const float* __restrict__ W2,
    const float* __restrict__ W1, unsigned short* __restrict__ Bp,
    const int* __restrict__ edst, int* __restrict__ counts)
{
    if (blockIdx.x < 448) {
        int i = blockIdx.x * 256 + threadIdx.x;
        const float* src; int rem;
        if (i < 81920) {
            int m = i >> 14; rem = i & 16383;
            src = (m == 0) ? Wq : (m == 1) ? Wk : (m == 2) ? Wv : (m == 3) ? Wout : W2;
        } else { rem = i - 81920; src = W1; }
        int j  = rem & 7;
        int l  = (rem >> 3) & 63;
        int ct = (rem >> 9) & 7;
        int ks = rem >> 12;
        int k  = ks * 32 + ((l >> 4) << 3) + j;
        int c  = (ct << 4) + (l & 15);
        Bp[i] = f2bf(src[k * 128 + c]);
    } else {
        for (int i = (blockIdx.x - 448) * 256 + threadIdx.x; i < NEDGE; i += 512 * 256)
            atomicAdd(&counts[edst[i]], 1);
    }
}

// ---------------------------------------------------------------------------
// Fused: prefix scan (block 0) + Q projection GEMM (blocks 1..313)
// ---------------------------------------------------------------------------
__global__ __launch_bounds__(256) void scan_qproj(const int* __restrict__ counts,
    int* __restrict__ starts, int* __restrict__ cursors,
    const float* __restrict__ right, const unsigned short* __restrict__ BpQ,
    unsigned short* __restrict__ qproj)
{
    if (blockIdx.x == 0) {
        const int t = threadIdx.x;
        const int CH = 79;                       // 256*79 >= 20000
        int lo = t * CH;
        int hi = lo + CH; if (hi > N_RIGHTC) hi = N_RIGHTC;
        int sum = 0;
        for (int i = lo; i < hi; ++i) sum += counts[i];
        int lane = t & 63, wv = t >> 6;
        int x = sum;
        #pragma unroll
        for (int o = 1; o < 64; o <<= 1) {
            int y = __shfl_up(x, o);
            if (lane >= o) x += y;
        }
        __shared__ int wsum[4], woff[4];
        if (lane == 63) wsum[wv] = x;
        __syncthreads();
        if (t == 0) {
            int run = 0;
            #pragma unroll
            for (int i = 0; i < 4; ++i) { woff[i] = run; run += wsum[i]; }
            starts[N_RIGHTC] = run;
        }
        __syncthreads();
        int run = x - sum + woff[wv];
        for (int i = lo; i < hi; ++i) {
            starts[i] = run; cursors[i] = run; run += counts[i];
        }
    } else {
        gemm_body<false, true>(right, BpQ, qproj, N_RIGHTC, blockIdx.x - 1, threadIdx.x);
    }
}

// ---------------------------------------------------------------------------
// Fused: CSR scatter with src/ef pre-gather (blocks 0..511) +
//        K/V projection GEMM (blocks 512..590)
// ---------------------------------------------------------------------------
__global__ __launch_bounds__(256) void scatter_kv(const int* __restrict__ edst,
    const int* __restrict__ esrc, const float4* __restrict__ ef,
    int* __restrict__ cursors, int* __restrict__ srcs, float4* __restrict__ efs,
    const float* __restrict__ left, const unsigned short* __restrict__ BpK,
    const unsigned short* __restrict__ BpV, unsigned short* __restrict__ K,
    unsigned short* __restrict__ V)
{
    if (blockIdx.x < 512) {
        for (int i = blockIdx.x * 256 + threadIdx.x; i < NEDGE; i += 512 * 256) {
            int d = edst[i];
            int p = atomicAdd(&cursors[d], 1);
            srcs[p] = esrc[i];
            efs[p]  = ef[i];
        }
    } else {
        const int bid = blockIdx.x - 512;
        const int tid = threadIdx.x;
        const int l  = tid & 63;
        const int w  = tid >> 6;
        const int r0 = bid * 64 + w * 16;
        const int arow = r0 + (l & 15);
        const int kl = (l >> 4) * 8;
        f32x4 acck[8], accv[8];
        #pragma unroll
        for (int ct = 0; ct < 8; ++ct) { acck[ct] = (f32x4){0,0,0,0}; accv[ct] = (f32x4){0,0,0,0}; }
        const bool aok = (arow < N_LEFTC);
        #pragma unroll
        for (int ks = 0; ks < 4; ++ks) {
            bf16x8 a = {0, 0, 0, 0, 0, 0, 0, 0};
            if (aok) a = loadA_f32(left + (size_t)arow * 128 + ks * 32 + kl);
            #pragma unroll
            for (int ct = 0; ct < 8; ++ct) {
                int fo = ((ks * 8 + ct) * 64 + l) << 3;
                bf16x8 bk = *(const bf16x8*)(BpK + fo);
                bf16x8 bv = *(const bf16x8*)(BpV + fo);
                acck[ct] = __builtin_amdgcn_mfma_f32_16x16x32_bf16(a, bk, acck[ct], 0, 0, 0);
                accv[ct] = __builtin_amdgcn_mfma_f32_16x16x32_bf16(a, bv, accv[ct], 0, 0, 0);
            }
        }
        const int orow = r0 + (l >> 4) * 4;
        const int oc   = l & 15;
        #pragma unroll
        for (int ct = 0; ct < 8; ++ct) {
            int col = ct * 16 + oc;
            #pragma unroll
            for (int r = 0; r < 4; ++r) {
                if (orow + r < N_LEFTC) {
                    K[(size_t)(orow + r) * 128 + col] = f2bf(acck[ct][r]);
                    V[(size_t)(orow + r) * 128 + col] = f2bf(accv[ct][r]);
                }
            }
        }
    }
}

// ---------------------------------------------------------------------------
// Fused edge attention. One WAVE per dst (4 waves/block); halves take
// [e0,mid) / [mid,e1), 4 edges batched (8 gather chains in flight / wave).
// Algebraic hoisting: q.ke = ef.tq (tq precomputed per dst/head);
// sum_i e_i*ve_i = (sum_i e_i*ef_i) @ Wve applied once in epilogue.
// ---------------------------------------------------------------------------
__global__ __launch_bounds__(256) void attn_kernel(
    const unsigned short* __restrict__ qp, const unsigned short* __restrict__ kp,
    const unsigned short* __restrict__ vp, const float4* __restrict__ efs,
    const int* __restrict__ srcs, const int* __restrict__ starts,
    const float* __restrict__ Wke, const float* __restrict__ Wve,
    unsigned short* __restrict__ agg)
{
    const int w    = threadIdx.x >> 6;
    const int l    = threadIdx.x & 63;
    const int d    = blockIdx.x * 4 + w;
    const int half = l >> 5;
    const int hl   = l & 31;
    const int c0   = hl * 4;

    u16x4 qu = *(const u16x4*)(qp + (size_t)d * 128 + c0);
    float qv[4] = { bf2f(qu[0]), bf2f(qu[1]), bf2f(qu[2]), bf2f(qu[3]) };

    // tq[f] = sum over this head's 16 dims of q_d * Wke[f][d]
    float tq[4];
    #pragma unroll
    for (int f = 0; f < 4; ++f) {
        float4 a = *(const float4*)(Wke + f * 128 + c0);
        float tp = qv[0] * a.x + qv[1] * a.y + qv[2] * a.z + qv[3] * a.w;
        tp += __shfl_xor(tp, 1);
        tp += __shfl_xor(tp, 2);
        tq[f] = tp;
    }

    const int e0 = starts[d], e1 = starts[d + 1];
    const int mid = (e0 + e1 + 1) >> 1;
    const int p0 = half ? mid : e0;
    const int pe = half ? e1 : mid;

    float s = 0.f;
    float av[4]  = {0.f, 0.f, 0.f, 0.f};
    float sef[4] = {0.f, 0.f, 0.f, 0.f};

    for (int p = p0; p < pe; p += 4) {
        int src_[4]; float4 ef_[4]; bool ok_[4];
        #pragma unroll
        for (int b = 0; b < 4; ++b) {
            int idx = p + b;
            ok_[b] = (idx < pe);
            int ii = ok_[b] ? idx : p0;
            src_[b] = srcs[ii];
            ef_[b]  = efs[ii];
        }
        u16x4 ku_[4], vu_[4];
        #pragma unroll
        for (int b = 0; b < 4; ++b) {
            ku_[b] = *(const u16x4*)(kp + (size_t)src_[b] * 128 + c0);
            vu_[b] = *(const u16x4*)(vp + (size_t)src_[b] * 128 + c0);
        }
        #pragma unroll
        for (int b = 0; b < 4; ++b) {
            float pp = qv[0] * bf2f(ku_[b][0]) + qv[1] * bf2f(ku_[b][1])
                     + qv[2] * bf2f(ku_[b][2]) + qv[3] * bf2f(ku_[b][3]);
            pp += __shfl_xor(pp, 1);
            pp += __shfl_xor(pp, 2);            // 16-dim k-dot within the quad
            float4 f = ef_[b];
            float lg = (pp + f.x * tq[0] + f.y * tq[1] + f.z * tq[2] + f.w * tq[3]) * 0.25f;
            float e = ok_[b] ? __expf(lg) : 0.f;
            s += e;
            av[0] += e * bf2f(vu_[b][0]); av[1] += e * bf2f(vu_[b][1]);
            av[2] += e * bf2f(vu_[b][2]); av[3] += e * bf2f(vu_[b][3]);
            sef[0] += e * f.x; sef[1] += e * f.y; sef[2] += e * f.z; sef[3] += e * f.w;
        }
    }
    // apply Wve once: av_j += sum_f sef_f * Wve[f][c0+j]
    #pragma unroll
    for (int f = 0; f < 4; ++f) {
        float4 b = *(const float4*)(Wve + f * 128 + c0);
        av[0] += sef[f] * b.x; av[1] += sef[f] * b.y;
        av[2] += sef[f] * b.z; av[3] += sef[f] * b.w;
    }
    s += __shfl_xor(s, 32);
    #pragma unroll
    for (int j = 0; j < 4; ++j) av[j] += __shfl_xor(av[j], 32);
    if (half == 0) {
        float inv = 1.f / (s + 1e-16f);
        u16x4 o = { f2bf(av[0] * inv), f2bf(av[1] * inv), f2bf(av[2] * inv), f2bf(av[3] * inv) };
        *(u16x4*)(agg + (size_t)d * 128 + c0) = o;
    }
}

// ---------------------------------------------------------------------------
// Wout GEMM (agg bf16 -> out0 bf16) with fused BN statistics (sum, sumsq)
// ---------------------------------------------------------------------------
__global__ __launch_bounds__(256) void gemm_out0(const unsigned short* __restrict__ A,
    const unsigned short* __restrict__ Bp, unsigned short* __restrict__ C,
    float* __restrict__ stats, int M)
{
    __shared__ float sds[256];
    sds[threadIdx.x] = 0.f;
    __syncthreads();

    const int l  = threadIdx.x & 63;
    const int w  = threadIdx.x >> 6;
    const int r0 = blockIdx.x * 64 + w * 16;
    const int arow = r0 + (l & 15);
    const int kl = (l >> 4) * 8;
    f32x4 acc[8];
    #pragma unroll
    for (int ct = 0; ct < 8; ++ct) acc[ct] = (f32x4){0.f, 0.f, 0.f, 0.f};
    const bool aok = (arow < M);
    #pragma unroll
    for (int ks = 0; ks < 4; ++ks) {
        bf16x8 a = {0, 0, 0, 0, 0, 0, 0, 0};
        if (aok) a = *(const bf16x8*)(A + (size_t)arow * 128 + ks * 32 + kl);
        #pragma unroll
        for (int ct = 0; ct < 8; ++ct) {
            bf16x8 b = *(const bf16x8*)(Bp + (((ks * 8 + ct) * 64 + l) << 3));
            acc[ct] = __builtin_amdgcn_mfma_f32_16x16x32_bf16(a, b, acc[ct], 0, 0, 0);
        }
    }
    const int orow = r0 + (l >> 4) * 4;
    const int oc   = l & 15;
    #pragma unroll
    for (int ct = 0; ct < 8; ++ct) {
        int col = ct * 16 + oc;
        float cs = 0.f, cq = 0.f;
        #pragma unroll
        for (int r = 0; r < 4; ++r) {
            if (orow + r < M) {
                float v = acc[ct][r];
                C[(size_t)(orow + r) * 128 + col] = f2bf(v);
                cs += v; cq += v * v;
            }
        }
        atomicAdd(&sds[col], cs);
        atomicAdd(&sds[128 + col], cq);
    }
    __syncthreads();
    atomicAdd(&stats[threadIdx.x], sds[threadIdx.x]);
}

// ---------------------------------------------------------------------------
// Fused tail: bn params from stats (in-block) ;
// h = relu([bn(out0), right] @ W1 + b1) -> LDS ; out = h @ W2 + b2
// ---------------------------------------------------------------------------
__global__ __launch_bounds__(256) void gemm_tail(const unsigned short* __restrict__ A1,
    const float* __restrict__ A2, const float* __restrict__ stats,
    const float* __restrict__ gamma, const float* __restrict__ beta,
    const unsigned short* __restrict__ Bp1, const float* __restrict__ b1,
    const unsigned short* __restrict__ Bp2, const float* __restrict__ b2,
    float* __restrict__ out, int M)
{
    __shared__ unsigned short h[64][136];
    __shared__ float sbn[256];
    if (threadIdx.x < 128) {
        int c = threadIdx.x;
        float mean = stats[c] * (1.f / N_RIGHTC);
        float var  = stats[128 + c] * (1.f / N_RIGHTC) - mean * mean;
        float sc   = gamma[c] * rsqrtf(var + 1e-5f);
        sbn[c]       = sc;
        sbn[128 + c] = beta[c] - mean * sc;
    }
    __syncthreads();

    const int l  = threadIdx.x & 63;
    const int w  = threadIdx.x >> 6;
    const int r0 = blockIdx.x * 64 + w * 16;
    const int arow = r0 + (l & 15);
    const int kl = (l >> 4) * 8;
    f32x4 acc[8];
    #pragma unroll
    for (int ct = 0; ct < 8; ++ct) acc[ct] = (f32x4){0.f, 0.f, 0.f, 0.f};
    const bool aok = (arow < M);
    #pragma unroll
    for (int ks = 0; ks < 8; ++ks) {
        bf16x8 a = {0, 0, 0, 0, 0, 0, 0, 0};
        if (aok) {
            if (ks < 4) {
                int k0 = ks * 32 + kl;
                bf16x8 raw = *(const bf16x8*)(A1 + (size_t)arow * 128 + k0);
                #pragma unroll
                for (int j = 0; j < 8; ++j)
                    a[j] = (short)f2bf(bf2f((unsigned short)raw[j]) * sbn[k0 + j] + sbn[128 + k0 + j]);
            } else {
                a = loadA_f32(A2 + (size_t)arow * 128 + (ks - 4) * 32 + kl);
            }
        }
        #pragma unroll
        for (int ct = 0; ct < 8; ++ct) {
            bf16x8 b = *(const bf16x8*)(Bp1 + (((ks * 8 + ct) * 64 + l) << 3));
            acc[ct] = __builtin_amdgcn_mfma_f32_16x16x32_bf16(a, b, acc[ct], 0, 0, 0);
        }
    }
    {
        const int lr0 = w * 16 + (l >> 4) * 4;
        const int oc  = l & 15;
        #pragma unroll
        for (int ct = 0; ct < 8; ++ct) {
            int col = ct * 16 + oc;
            float bv = b1[col];
            #pragma unroll
            for (int r = 0; r < 4; ++r)
                h[lr0 + r][col] = f2bf(fmaxf(acc[ct][r] + bv, 0.f));
        }
    }
    __syncthreads();
    #pragma unroll
    for (int ct = 0; ct < 8; ++ct) acc[ct] = (f32x4){0.f, 0.f, 0.f, 0.f};
    const int lrow = w * 16 + (l & 15);
    #pragma unroll
    for (int ks = 0; ks < 4; ++ks) {
        bf16x8 a = *(const bf16x8*)&h[lrow][ks * 32 + kl];
        #pragma unroll
        for (int ct = 0; ct < 8; ++ct) {
            bf16x8 b = *(const bf16x8*)(Bp2 + (((ks * 8 + ct) * 64 + l) << 3));
            acc[ct] = __builtin_amdgcn_mfma_f32_16x16x32_bf16(a, b, acc[ct], 0, 0, 0);
        }
    }
    const int orow = r0 + (l >> 4) * 4;
    const int oc   = l & 15;
    #pragma unroll
    for (int ct = 0; ct < 8; ++ct) {
        int col = ct * 16 + oc;
        float bv = b2[col];
        #pragma unroll
        for (int r = 0; r < 4; ++r)
            if (orow + r < M)
                out[(size_t)(orow + r) * 128 + col] = acc[ct][r] + bv;
    }
}

// ---------------------------------------------------------------------------
// launch
// ---------------------------------------------------------------------------
extern "C" void kernel_launch(void* const* d_in, const int* in_sizes, int n_in,
                              void* d_out, int out_size, void* d_ws, size_t ws_size,
                              hipStream_t stream)
{
    const float* left  = (const float*)d_in[0];
    const float* right = (const float*)d_in[1];
    const float* ef    = (const float*)d_in[2];
    const int*   esrc  = (const int*)d_in[3];
    const int*   edst  = (const int*)d_in[4];
    const float* Wq    = (const float*)d_in[5];
    const float* Wk    = (const float*)d_in[6];
    const float* Wv    = (const float*)d_in[7];
    const float* Wke   = (const float*)d_in[8];
    const float* Wve   = (const float*)d_in[9];
    const float* Wout  = (const float*)d_in[10];
    const float* gamma = (const float*)d_in[11];
    const float* beta  = (const float*)d_in[12];
    const float* W1    = (const float*)d_in[13];
    const float* b1    = (const float*)d_in[14];
    const float* W2    = (const float*)d_in[15];
    const float* b2    = (const float*)d_in[16];
    float* out = (float*)d_out;

    char* ws = (char*)d_ws;
    int*   counts  = (int*)  (ws + 0);            //  80,000
    float* stats   = (float*)(ws + 80000);        //   1,024  (memset together: 81,024)
    int*   starts  = (int*)  (ws + 81024);        //  80,128
    int*   cursors = (int*)  (ws + 161152);       //  80,000
    unsigned short* Bp = (unsigned short*)(ws + 241152);       // 229,376
    unsigned short* qproj = (unsigned short*)(ws + 470528);    // 5,120,000
    unsigned short* kproj = (unsigned short*)(ws + 5590528);   // 1,280,000
    unsigned short* vproj = (unsigned short*)(ws + 6870528);   // 1,280,000
    unsigned short* agg   = (unsigned short*)(ws + 8150528);   // 5,120,000
    unsigned short* out0  = (unsigned short*)(ws + 13270528);  // 5,120,000
    int*    srcs   = (int*)   (ws + 18390528);                 // 1,600,000
    float4* efs    = (float4*)(ws + 19990528);                 // 6,400,000 -> 26,390,528

    hipMemsetAsync(counts, 0, 81024, stream);

    pack_hist<<<960, 256, 0, stream>>>(Wq, Wk, Wv, Wout, W2, W1, Bp, edst, counts);

    scan_qproj<<<314, 256, 0, stream>>>(counts, starts, cursors, right, Bp, qproj);

    scatter_kv<<<591, 256, 0, stream>>>(edst, esrc, (const float4*)ef, cursors, srcs, efs,
                                        left, Bp + 16384, Bp + 32768, kproj, vproj);

    attn_kernel<<<N_RIGHTC / 4, 256, 0, stream>>>(qproj, kproj, vproj, efs, srcs,
                                                  starts, Wke, Wve, agg);

    gemm_out0<<<(N_RIGHTC + 63) / 64, 256, 0, stream>>>(agg, Bp + 49152, out0, stats, N_RIGHTC);

    gemm_tail<<<(N_RIGHTC + 63) / 64, 256, 0, stream>>>(out0, right, stats, gamma, beta,
                                                        Bp + 81920, b1, Bp + 65536, b2,
                                                        out, N_RIGHTC);
}